// Round 1
// baseline (1106.845 us; speedup 1.0000x reference)
//
#include <hip/hip_runtime.h>
#include <cstddef>

#define NB 8
#define CQK 64
#define CV 256
#define WW 64
#define NPIX 4096
#define MPIX 1024
#define QT 16

// out[c][o] = in[o][c]; in is [O][Cn]
__global__ void transpose_k(const float* __restrict__ in, float* __restrict__ out,
                            int O, int Cn) {
  int idx = blockIdx.x * 256 + threadIdx.x;
  if (idx >= O * Cn) return;
  int o = idx / Cn, c = idx - o * Cn;
  out[(size_t)c * O + o] = in[idx];
}

// out[b][oc0+4ty+i][n0+4tx+j] = epi( sum_c Wt[c][oc]*xin[b][c][n], bias )
// Wt is [CINT][OC_total] (pre-transposed). EPI==1: out = gamma*(acc+bias)+resid.
template<int CINT, int EPI>
__global__ __launch_bounds__(256)
void conv_tile(const float* __restrict__ xin, const float* __restrict__ Wt,
               const float* __restrict__ bias, float* __restrict__ out,
               int OC_total, const float* __restrict__ resid,
               const float* __restrict__ gamma_p)
{
  __shared__ __align__(16) float xs[64][64];
  __shared__ __align__(16) float wsh[64][64];
  const int b = blockIdx.z, oc0 = blockIdx.y * 64, n0 = blockIdx.x * 64;
  const int tid = threadIdx.x;
  const int tx = tid & 15, ty = tid >> 4;
  float acc[4][4] = {};
  for (int c0 = 0; c0 < CINT; c0 += 64) {
    #pragma unroll
    for (int k = 0; k < 16; ++k) {
      int idx = tid + k * 256;
      int r = idx >> 6, col = idx & 63;
      xs[r][col]  = xin[((size_t)b * CINT + c0 + r) * NPIX + n0 + col];
      wsh[r][col] = Wt[(size_t)(c0 + r) * OC_total + oc0 + col];
    }
    __syncthreads();
    #pragma unroll 8
    for (int c = 0; c < 64; ++c) {
      float4 wv = *(const float4*)&wsh[c][ty * 4];
      float4 xv = *(const float4*)&xs[c][tx * 4];
      float wr[4] = {wv.x, wv.y, wv.z, wv.w};
      float xr[4] = {xv.x, xv.y, xv.z, xv.w};
      #pragma unroll
      for (int i = 0; i < 4; ++i)
        #pragma unroll
        for (int j = 0; j < 4; ++j)
          acc[i][j] += wr[i] * xr[j];
    }
    __syncthreads();
  }
  const float gm = (EPI == 1) ? gamma_p[0] : 0.0f;
  #pragma unroll
  for (int i = 0; i < 4; ++i) {
    int oc = oc0 + ty * 4 + i;
    float bs = bias[oc];
    float r4[4];
    #pragma unroll
    for (int j = 0; j < 4; ++j) {
      float val = acc[i][j] + bs;
      if (EPI == 1)
        val = gm * val + resid[((size_t)b * OC_total + oc) * NPIX + n0 + tx * 4 + j];
      r4[j] = val;
    }
    float4 ov; ov.x = r4[0]; ov.y = r4[1]; ov.z = r4[2]; ov.w = r4[3];
    *(float4*)&out[((size_t)b * OC_total + oc) * NPIX + n0 + tx * 4] = ov;
  }
}

// g[b][c][m] = max 2x2 of gfull[b][c][h][w]
__global__ void pool_g_k(const float* __restrict__ gf, float* __restrict__ g) {
  int idx = blockIdx.x * 256 + threadIdx.x;
  if (idx >= NB * CQK * MPIX) return;
  int m = idx & 1023;
  int c = (idx >> 10) & 63;
  int b = idx >> 16;
  int hp = m >> 5, wp = m & 31;
  const float* src = gf + ((size_t)(b * CQK + c)) * NPIX + (hp * 2) * WW + wp * 2;
  g[idx] = fmaxf(fmaxf(src[0], src[1]), fmaxf(src[WW], src[WW + 1]));
}

// vt[b][m][cv] = max 2x2 of vfull[b][cv][h][w]  (pool + transpose)
__global__ void pool_tr_v_k(const float* __restrict__ vf, float* __restrict__ vt) {
  int idx = blockIdx.x * 256 + threadIdx.x;
  if (idx >= NB * MPIX * CV) return;
  int cv = idx & 255;
  int m = (idx >> 8) & 1023;
  int b = idx >> 18;
  int hp = m >> 5, wp = m & 31;
  const float* src = vf + ((size_t)b * CV + cv) * NPIX + (hp * 2) * WW + wp * 2;
  vt[idx] = fmaxf(fmaxf(src[0], src[1]), fmaxf(src[WW], src[WW + 1]));
}

// Fused attention: per (b, 16-query tile): s = f^T g -> softmax(m) -> o = v beta^T
__global__ __launch_bounds__(256)
void attn_kernel(const float* __restrict__ f, const float* __restrict__ g,
                 const float* __restrict__ vt, float* __restrict__ o)
{
  __shared__ __align__(16) float fq[CQK][QT];     // 4 KB
  __shared__ __align__(16) float st[MPIX][20];    // 80 KB (pad 20: f4-aligned, conflict-free)
  __shared__ float rinv_s[QT];
  const int b = blockIdx.y;
  const int n0 = blockIdx.x * QT;
  const int tid = threadIdx.x;

  #pragma unroll
  for (int k = 0; k < 4; ++k) {
    int idx = tid + k * 256;
    int c = idx >> 4, q = idx & 15;
    fq[c][q] = f[((size_t)b * CQK + c) * NPIX + n0 + q];
  }
  __syncthreads();

  { // s step: thread owns m = tid + 256k, k=0..3; acc over 16 queries
    float acc[4][QT];
    #pragma unroll
    for (int k = 0; k < 4; ++k)
      #pragma unroll
      for (int q = 0; q < QT; ++q) acc[k][q] = 0.0f;
    for (int c = 0; c < CQK; ++c) {
      float gv[4];
      #pragma unroll
      for (int k = 0; k < 4; ++k)
        gv[k] = g[((size_t)b * CQK + c) * MPIX + k * 256 + tid];
      float4 fa = *(const float4*)&fq[c][0];
      float4 fb = *(const float4*)&fq[c][4];
      float4 fc = *(const float4*)&fq[c][8];
      float4 fd = *(const float4*)&fq[c][12];
      float fv[QT] = {fa.x, fa.y, fa.z, fa.w, fb.x, fb.y, fb.z, fb.w,
                      fc.x, fc.y, fc.z, fc.w, fd.x, fd.y, fd.z, fd.w};
      #pragma unroll
      for (int k = 0; k < 4; ++k)
        #pragma unroll
        for (int q = 0; q < QT; ++q)
          acc[k][q] += fv[q] * gv[k];
    }
    #pragma unroll
    for (int k = 0; k < 4; ++k) {
      int m = k * 256 + tid;
      #pragma unroll
      for (int q4 = 0; q4 < 4; ++q4) {
        float4 w;
        w.x = acc[k][q4 * 4 + 0]; w.y = acc[k][q4 * 4 + 1];
        w.z = acc[k][q4 * 4 + 2]; w.w = acc[k][q4 * 4 + 3];
        *(float4*)&st[m][q4 * 4] = w;
      }
    }
  }
  __syncthreads();

  { // softmax over m per query; 16-lane team per query row
    const int q = tid >> 4, j = tid & 15;
    float mx = -3.0e38f;
    for (int k = 0; k < MPIX / 16; ++k)
      mx = fmaxf(mx, st[k * 16 + j][q]);
    #pragma unroll
    for (int d = 1; d < 16; d <<= 1)
      mx = fmaxf(mx, __shfl_xor(mx, d, 16));
    float sm = 0.0f;
    for (int k = 0; k < MPIX / 16; ++k) {
      float e = expf(st[k * 16 + j][q] - mx);
      st[k * 16 + j][q] = e;
      sm += e;
    }
    #pragma unroll
    for (int d = 1; d < 16; d <<= 1)
      sm += __shfl_xor(sm, d, 16);
    if (j == 0) rinv_s[q] = 1.0f / sm;
  }
  __syncthreads();

  { // PV: thread = (m-quarter kk, 4 cv); acc[16 q][4 cv]
    const int kk = tid >> 6;
    const int cv4 = (tid & 63) * 4;
    float acc[QT][4];
    #pragma unroll
    for (int q = 0; q < QT; ++q)
      #pragma unroll
      for (int i = 0; i < 4; ++i) acc[q][i] = 0.0f;
    #pragma unroll 2
    for (int mi = 0; mi < MPIX / 4; ++mi) {
      int m = kk * (MPIX / 4) + mi;
      float4 vv = *(const float4*)&vt[((size_t)b * MPIX + m) * CV + cv4];
      #pragma unroll
      for (int q4 = 0; q4 < 4; ++q4) {
        float4 bb = *(const float4*)&st[m][q4 * 4];
        float br[4] = {bb.x, bb.y, bb.z, bb.w};
        #pragma unroll
        for (int qq = 0; qq < 4; ++qq) {
          acc[q4 * 4 + qq][0] += br[qq] * vv.x;
          acc[q4 * 4 + qq][1] += br[qq] * vv.y;
          acc[q4 * 4 + qq][2] += br[qq] * vv.z;
          acc[q4 * 4 + qq][3] += br[qq] * vv.w;
        }
      }
    }
    __syncthreads();               // all reads of st(beta) done
    float* part = &st[0][0];       // reuse: [3][QT][CV] partials
    if (kk > 0) {
      #pragma unroll
      for (int q = 0; q < QT; ++q) {
        float4 w;
        w.x = acc[q][0]; w.y = acc[q][1]; w.z = acc[q][2]; w.w = acc[q][3];
        *(float4*)&part[(((kk - 1) * QT + q) * CV) + cv4] = w;
      }
    }
    __syncthreads();
    float* obuf = part + 3 * QT * CV;   // [QT][260]
    if (kk == 0) {
      #pragma unroll
      for (int q = 0; q < QT; ++q) {
        float4 p0 = *(const float4*)&part[((0 * QT + q) * CV) + cv4];
        float4 p1 = *(const float4*)&part[((1 * QT + q) * CV) + cv4];
        float4 p2 = *(const float4*)&part[((2 * QT + q) * CV) + cv4];
        float rv = rinv_s[q];
        float4 w;
        w.x = (acc[q][0] + p0.x + p1.x + p2.x) * rv;
        w.y = (acc[q][1] + p0.y + p1.y + p2.y) * rv;
        w.z = (acc[q][2] + p0.z + p1.z + p2.z) * rv;
        w.w = (acc[q][3] + p0.w + p1.w + p2.w) * rv;
        *(float4*)&obuf[q * 260 + cv4] = w;
      }
    }
    __syncthreads();
    #pragma unroll
    for (int it = 0; it < 16; ++it) {
      int q = tid & 15;
      int cv = (tid >> 4) + it * 16;
      o[((size_t)b * CV + cv) * NPIX + n0 + q] = obuf[q * 260 + cv];
    }
  }
}

extern "C" void kernel_launch(void* const* d_in, const int* in_sizes, int n_in,
                              void* d_out, int out_size, void* d_ws, size_t ws_size,
                              hipStream_t stream) {
  const float* x     = (const float*)d_in[0];
  const float* Wf    = (const float*)d_in[1];
  const float* bf    = (const float*)d_in[2];
  const float* Wg    = (const float*)d_in[3];
  const float* bg    = (const float*)d_in[4];
  const float* Wh    = (const float*)d_in[5];
  const float* bh    = (const float*)d_in[6];
  const float* Wv    = (const float*)d_in[7];
  const float* bv    = (const float*)d_in[8];
  const float* gamma = (const float*)d_in[9];
  float* out = (float*)d_out;
  float* w   = (float*)d_ws;

  // ws layout (floats); v_full and o overlay in ws_big. Total 62.1 MB.
  float* ws_f     = w;                    // [8][64][4096]
  float* ws_g     = ws_f + 2097152;       // [8][64][1024]
  float* ws_vt    = ws_g + 524288;        // [8][1024][256]
  float* ws_big   = ws_vt + 2097152;      // [8][256][4096]: v_full then o
  float* ws_gfull = ws_big + 8388608;     // [8][64][4096]
  float* wft      = ws_gfull + 2097152;   // [512][64]
  float* wgt      = wft + 32768;          // [512][64]
  float* wht      = wgt + 32768;          // [512][256]
  float* wvt      = wht + 131072;         // [256][512]

  transpose_k<<<(64 * 512 + 255) / 256, 256, 0, stream>>>(Wf, wft, 64, 512);
  transpose_k<<<(64 * 512 + 255) / 256, 256, 0, stream>>>(Wg, wgt, 64, 512);
  transpose_k<<<(256 * 512 + 255) / 256, 256, 0, stream>>>(Wh, wht, 256, 512);
  transpose_k<<<(512 * 256 + 255) / 256, 256, 0, stream>>>(Wv, wvt, 512, 256);

  conv_tile<512, 0><<<dim3(64, 1, NB), 256, 0, stream>>>(x, wft, bf, ws_f, 64, nullptr, nullptr);
  conv_tile<512, 0><<<dim3(64, 1, NB), 256, 0, stream>>>(x, wgt, bg, ws_gfull, 64, nullptr, nullptr);
  pool_g_k<<<(NB * CQK * MPIX + 255) / 256, 256, 0, stream>>>(ws_gfull, ws_g);
  conv_tile<512, 0><<<dim3(64, 4, NB), 256, 0, stream>>>(x, wht, bh, ws_big, 256, nullptr, nullptr);
  pool_tr_v_k<<<(NB * MPIX * CV + 255) / 256, 256, 0, stream>>>(ws_big, ws_vt);
  attn_kernel<<<dim3(NPIX / QT, NB), 256, 0, stream>>>(ws_f, ws_g, ws_vt, ws_big);
  conv_tile<256, 1><<<dim3(64, 8, NB), 256, 0, stream>>>(ws_big, wvt, bv, out, 512, x, gamma);
}

// Round 2
// 574.603 us; speedup vs baseline: 1.9263x; 1.9263x over previous
//
#include <hip/hip_runtime.h>
#include <cstddef>

typedef __attribute__((ext_vector_type(4))) float f32x4;
typedef __attribute__((ext_vector_type(8))) short bf16x8;

#define MFMA16(A, B, C) __builtin_amdgcn_mfma_f32_16x16x32_bf16(A, B, C, 0, 0, 0)

__device__ __forceinline__ unsigned short f2bf(float f) {
  unsigned u = __float_as_uint(f);
  u += 0x7fffu + ((u >> 16) & 1u);
  return (unsigned short)(u >> 16);
}
__device__ __forceinline__ float bf2f(unsigned short s) {
  return __uint_as_float(((unsigned)s) << 16);
}

// ---------- small transforms ----------

__global__ void transpose_k(const float* __restrict__ in, float* __restrict__ out,
                            int O, int Cn) {
  int idx = blockIdx.x * 256 + threadIdx.x;
  if (idx >= O * Cn) return;
  int o = idx / Cn, c = idx - o * Cn;
  out[(size_t)c * O + o] = in[idx];
}

__global__ void cast_bf16_k(const float* __restrict__ in, unsigned short* __restrict__ out, int n) {
  int i = blockIdx.x * 256 + threadIdx.x;
  if (i < n) out[i] = f2bf(in[i]);
}

// x[b][512][4096] fp32 -> xT[b][4096][512] bf16
__global__ __launch_bounds__(256)
void xT_k(const float* __restrict__ x, unsigned short* __restrict__ xT) {
  __shared__ float t[64][65];
  int b = blockIdx.z, c0 = blockIdx.y * 64, n0 = blockIdx.x * 64;
  int tid = threadIdx.x;
  #pragma unroll
  for (int k = 0; k < 16; ++k) {
    int idx = tid + k * 256; int r = idx >> 6, col = idx & 63;
    t[r][col] = x[((size_t)(b * 512 + c0 + r)) * 4096 + n0 + col];
  }
  __syncthreads();
  #pragma unroll
  for (int k = 0; k < 16; ++k) {
    int idx = tid + k * 256; int r = idx >> 6, col = idx & 63; // r=n_local col=c_local
    xT[((size_t)b * 4096 + n0 + r) * 512 + c0 + col] = f2bf(t[col][r]);
  }
}

// f[b][64][4096] fp32 -> fT_hi/lo[b][4096][64] bf16 (split precision)
__global__ __launch_bounds__(256)
void splitT_f_k(const float* __restrict__ f, unsigned short* __restrict__ fhi,
                unsigned short* __restrict__ flo) {
  __shared__ float t[64][65];
  int b = blockIdx.y, n0 = blockIdx.x * 64;
  int tid = threadIdx.x;
  #pragma unroll
  for (int k = 0; k < 16; ++k) {
    int idx = tid + k * 256; int r = idx >> 6, col = idx & 63;   // r=c col=n
    t[r][col] = f[((size_t)(b * 64 + r)) * 4096 + n0 + col];
  }
  __syncthreads();
  #pragma unroll
  for (int k = 0; k < 16; ++k) {
    int idx = tid + k * 256; int r = idx >> 6, col = idx & 63;   // r=n col=c
    float v = t[col][r];
    unsigned short h = f2bf(v);
    size_t o = ((size_t)b * 4096 + n0 + r) * 64 + col;
    fhi[o] = h;
    flo[o] = f2bf(v - bf2f(h));
  }
}

// g[b][64][4096] fp32 -> pooled gT_hi/lo[b][1024][64] bf16
__global__ __launch_bounds__(256)
void poolsplitT_g_k(const float* __restrict__ g, unsigned short* __restrict__ ghi,
                    unsigned short* __restrict__ glo) {
  __shared__ float t[64][129];
  int b = blockIdx.y, hp = blockIdx.x;  // hp 0..31
  int tid = threadIdx.x;
  #pragma unroll
  for (int k = 0; k < 32; ++k) {
    int idx = tid + k * 256; int c = idx >> 7, nl = idx & 127;
    t[c][nl] = g[((size_t)(b * 64 + c)) * 4096 + hp * 128 + nl];
  }
  __syncthreads();
  #pragma unroll
  for (int k = 0; k < 8; ++k) {
    int idx = tid + k * 256; int wp = idx >> 6, c = idx & 63;   // 32 wp x 64 c
    float v = fmaxf(fmaxf(t[c][2 * wp], t[c][2 * wp + 1]),
                    fmaxf(t[c][64 + 2 * wp], t[c][65 + 2 * wp]));
    unsigned short h = f2bf(v);
    size_t o = ((size_t)b * 1024 + hp * 32 + wp) * 64 + c;
    ghi[o] = h;
    glo[o] = f2bf(v - bf2f(h));
  }
}

// vT[b][4096][256] bf16 -> v_pool[b][256][1024] bf16
__global__ void pool_v_k(const unsigned short* __restrict__ vT, unsigned short* __restrict__ vp) {
  int idx = blockIdx.x * 256 + threadIdx.x;          // (b*256+cv)*1024+m
  int m = idx & 1023, cv = (idx >> 10) & 255, b = idx >> 18;
  int hp = m >> 5, wp = m & 31;
  int n = hp * 128 + wp * 2;
  size_t base = ((size_t)b * 4096 + n) * 256 + cv;
  float a0 = bf2f(vT[base]), a1 = bf2f(vT[base + 256]);
  float a2 = bf2f(vT[base + 64 * 256]), a3 = bf2f(vT[base + 64 * 256 + 256]);
  vp[idx] = f2bf(fmaxf(fmaxf(a0, a1), fmaxf(a2, a3)));
}

// ---------- fp32 tile conv (f and g: precision-critical, cheap) ----------

template<int CINT>
__global__ __launch_bounds__(256)
void conv_tile(const float* __restrict__ xin, const float* __restrict__ Wt,
               const float* __restrict__ bias, float* __restrict__ out, int OC_total)
{
  __shared__ __align__(16) float xs[64][64];
  __shared__ __align__(16) float wsh[64][64];
  const int b = blockIdx.z, oc0 = blockIdx.y * 64, n0 = blockIdx.x * 64;
  const int tid = threadIdx.x;
  const int tx = tid & 15, ty = tid >> 4;
  float acc[4][4] = {};
  for (int c0 = 0; c0 < CINT; c0 += 64) {
    #pragma unroll
    for (int k = 0; k < 16; ++k) {
      int idx = tid + k * 256;
      int r = idx >> 6, col = idx & 63;
      xs[r][col]  = xin[((size_t)(b * CINT + c0 + r)) * 4096 + n0 + col];
      wsh[r][col] = Wt[(size_t)(c0 + r) * OC_total + oc0 + col];
    }
    __syncthreads();
    #pragma unroll 8
    for (int c = 0; c < 64; ++c) {
      float4 wv = *(const float4*)&wsh[c][ty * 4];
      float4 xv = *(const float4*)&xs[c][tx * 4];
      float wr[4] = {wv.x, wv.y, wv.z, wv.w};
      float xr[4] = {xv.x, xv.y, xv.z, xv.w};
      #pragma unroll
      for (int i = 0; i < 4; ++i)
        #pragma unroll
        for (int j = 0; j < 4; ++j)
          acc[i][j] += wr[i] * xr[j];
    }
    __syncthreads();
  }
  #pragma unroll
  for (int i = 0; i < 4; ++i) {
    int oc = oc0 + ty * 4 + i;
    float bs = bias[oc];
    float4 ov;
    ov.x = acc[i][0] + bs; ov.y = acc[i][1] + bs;
    ov.z = acc[i][2] + bs; ov.w = acc[i][3] + bs;
    *(float4*)&out[((size_t)(b * OC_total + oc)) * 4096 + n0 + tx * 4] = ov;
  }
}

// ---------- bf16 MFMA conv: D[n][oc] = sum_k A[n][k] * W[oc][k] ----------
// EPI 0: out bf16 [b][4096][OC] (+bias).  EPI 1: out fp32 [b][OC][4096] = gamma*(acc+bias)+resid.

template<int K, int EPI>
__global__ __launch_bounds__(256)
void conv_mfma(const unsigned short* __restrict__ A, const unsigned short* __restrict__ W,
               const float* __restrict__ bias, void* __restrict__ outp, int OC,
               const float* __restrict__ resid, const float* __restrict__ gamma_p)
{
  __shared__ float lds[64][65];
  const int b = blockIdx.z, oc0 = blockIdx.y * 64, n0 = blockIdx.x * 64;
  const int tid = threadIdx.x, w = tid >> 6, lane = tid & 63, q = lane & 15, qt = lane >> 4;
  const unsigned short* Ap = A + ((size_t)b * 4096 + n0 + w * 16 + q) * K + qt * 8;

  f32x4 acc[4];
  #pragma unroll
  for (int ot = 0; ot < 4; ++ot) acc[ot] = (f32x4){0.f, 0.f, 0.f, 0.f};

  for (int ks = 0; ks < K / 32; ++ks) {
    bf16x8 av = *(const bf16x8*)(Ap + ks * 32);
    #pragma unroll
    for (int ot = 0; ot < 4; ++ot) {
      bf16x8 bv = *(const bf16x8*)(W + ((size_t)(oc0 + ot * 16 + q)) * K + ks * 32 + qt * 8);
      acc[ot] = MFMA16(av, bv, acc[ot]);
    }
  }
  #pragma unroll
  for (int ot = 0; ot < 4; ++ot)
    #pragma unroll
    for (int r = 0; r < 4; ++r)
      lds[w * 16 + qt * 4 + r][ot * 16 + q] = acc[ot][r];
  __syncthreads();

  const float gm = (EPI == 1) ? gamma_p[0] : 0.0f;
  #pragma unroll
  for (int it = 0; it < 16; ++it) {
    int nl  = (EPI == 1) ? (tid & 63) : ((tid >> 6) + it * 4);
    int ocl = (EPI == 1) ? ((tid >> 6) + it * 4) : (tid & 63);
    float v = lds[nl][ocl] + bias[oc0 + ocl];
    if (EPI == 1) {
      size_t o = ((size_t)(b * OC) + oc0 + ocl) * 4096 + n0 + nl;
      ((float*)outp)[o] = gm * v + resid[o];
    } else {
      ((unsigned short*)outp)[((size_t)b * 4096 + n0 + nl) * OC + oc0 + ocl] = f2bf(v);
    }
  }
}

// ---------- fused attention: sT = g^T f (split-bf16), softmax, o^T = v P ----------

#define PROW 1032   // P row stride in bf16 elems (pad 8)

__global__ __launch_bounds__(256, 3)
void attn_mfma(const unsigned short* __restrict__ fhi, const unsigned short* __restrict__ flo,
               const unsigned short* __restrict__ ghi, const unsigned short* __restrict__ glo,
               const unsigned short* __restrict__ vp, unsigned short* __restrict__ oT)
{
  __shared__ unsigned short P[16 * PROW];   // 33 KB
  __shared__ float redm[4][16], reds[4][16];
  const int b = blockIdx.y, n0 = blockIdx.x * 16;
  const int tid = threadIdx.x, w = tid >> 6, lane = tid & 63, q = lane & 15, qt = lane >> 4;

  // B-fragments of f (col = q, k = c)
  const size_t fbase = ((size_t)b * 4096 + n0 + q) * 64 + qt * 8;
  bf16x8 fh0 = *(const bf16x8*)(fhi + fbase);
  bf16x8 fh1 = *(const bf16x8*)(fhi + fbase + 32);
  bf16x8 fl0 = *(const bf16x8*)(flo + fbase);
  bf16x8 fl1 = *(const bf16x8*)(flo + fbase + 32);

  f32x4 sa[16];
  #pragma unroll
  for (int t = 0; t < 16; ++t) sa[t] = (f32x4){0.f, 0.f, 0.f, 0.f};

  // sT[m][q], wave owns m-range w*256 .. +255 (16 tiles)
  #pragma unroll
  for (int t = 0; t < 16; ++t) {
    const size_t gbase = ((size_t)b * 1024 + w * 256 + t * 16 + q) * 64 + qt * 8;
    bf16x8 ah0 = *(const bf16x8*)(ghi + gbase);
    bf16x8 ah1 = *(const bf16x8*)(ghi + gbase + 32);
    bf16x8 al0 = *(const bf16x8*)(glo + gbase);
    bf16x8 al1 = *(const bf16x8*)(glo + gbase + 32);
    sa[t] = MFMA16(ah0, fh0, sa[t]);
    sa[t] = MFMA16(ah1, fh1, sa[t]);
    sa[t] = MFMA16(ah0, fl0, sa[t]);
    sa[t] = MFMA16(ah1, fl1, sa[t]);
    sa[t] = MFMA16(al0, fh0, sa[t]);
    sa[t] = MFMA16(al1, fh1, sa[t]);
  }

  // softmax over m. Lane holds col q, rows m = w*256 + t*16 + qt*4 + r.
  float mx = -3.0e38f;
  #pragma unroll
  for (int t = 0; t < 16; ++t)
    mx = fmaxf(mx, fmaxf(fmaxf(sa[t][0], sa[t][1]), fmaxf(sa[t][2], sa[t][3])));
  mx = fmaxf(mx, __shfl_xor(mx, 16));
  mx = fmaxf(mx, __shfl_xor(mx, 32));
  if (lane < 16) redm[w][lane] = mx;
  __syncthreads();
  const float gmx = fmaxf(fmaxf(redm[0][q], redm[1][q]), fmaxf(redm[2][q], redm[3][q]));

  float sum = 0.f;
  #pragma unroll
  for (int t = 0; t < 16; ++t) {
    #pragma unroll
    for (int r = 0; r < 4; ++r) {
      float p = __expf(sa[t][r] - gmx);
      sa[t][r] = p;
      sum += p;
    }
  }
  sum += __shfl_xor(sum, 16);
  sum += __shfl_xor(sum, 32);
  if (lane < 16) reds[w][lane] = sum;

  // write P (unnormalized, bf16) to LDS [q][m]
  #pragma unroll
  for (int t = 0; t < 16; ++t) {
    unsigned lo = (unsigned)f2bf(sa[t][0]) | ((unsigned)f2bf(sa[t][1]) << 16);
    unsigned hi = (unsigned)f2bf(sa[t][2]) | ((unsigned)f2bf(sa[t][3]) << 16);
    uint2 pk; pk.x = lo; pk.y = hi;
    *(uint2*)(&P[q * PROW + w * 256 + t * 16 + qt * 4]) = pk;
  }
  __syncthreads();
  const float rinv = 1.0f / (reds[0][q] + reds[1][q] + reds[2][q] + reds[3][q]);

  // PV: wave owns 4 cv-tiles (64 cv), full m. D[cv][q].
  f32x4 oacc[4];
  #pragma unroll
  for (int c4 = 0; c4 < 4; ++c4) oacc[c4] = (f32x4){0.f, 0.f, 0.f, 0.f};
  #pragma unroll 4
  for (int ks = 0; ks < 32; ++ks) {
    bf16x8 pb = *(const bf16x8*)(&P[q * PROW + ks * 32 + qt * 8]);
    #pragma unroll
    for (int c4 = 0; c4 < 4; ++c4) {
      const size_t vb = ((size_t)b * 256 + (w * 4 + c4) * 16 + q) * 1024 + ks * 32 + qt * 8;
      oacc[c4] = MFMA16(*(const bf16x8*)(vp + vb), pb, oacc[c4]);
    }
  }
  // epilogue: oT[b][n0+q][cv], scale by rinv
  #pragma unroll
  for (int c4 = 0; c4 < 4; ++c4) {
    unsigned lo = (unsigned)f2bf(oacc[c4][0] * rinv) | ((unsigned)f2bf(oacc[c4][1] * rinv) << 16);
    unsigned hi = (unsigned)f2bf(oacc[c4][2] * rinv) | ((unsigned)f2bf(oacc[c4][3] * rinv) << 16);
    uint2 pk; pk.x = lo; pk.y = hi;
    *(uint2*)(oT + ((size_t)b * 4096 + n0 + q) * 256 + (w * 4 + c4) * 16 + qt * 4) = pk;
  }
}

// ---------- launch ----------

extern "C" void kernel_launch(void* const* d_in, const int* in_sizes, int n_in,
                              void* d_out, int out_size, void* d_ws, size_t ws_size,
                              hipStream_t stream) {
  const float* x     = (const float*)d_in[0];
  const float* Wf    = (const float*)d_in[1];
  const float* bf    = (const float*)d_in[2];
  const float* Wg    = (const float*)d_in[3];
  const float* bg    = (const float*)d_in[4];
  const float* Wh    = (const float*)d_in[5];
  const float* bh    = (const float*)d_in[6];
  const float* Wv    = (const float*)d_in[7];
  const float* bv    = (const float*)d_in[8];
  const float* gamma = (const float*)d_in[9];
  float* out = (float*)d_out;
  char* w = (char*)d_ws;

  // region A: xT bf16 (32 MB); v_pool overlays A head after v-conv consumes xT
  unsigned short* xT     = (unsigned short*)(w);                    // 33,554,432 B
  unsigned short* v_pool = (unsigned short*)(w);                    //  4,194,304 B (after xT dead)
  // region B (16 MB): f/g fp32 -> vT bf16 -> oT bf16 (sequential overlays)
  char* B0 = w + 33554432;
  float* ws_f            = (float*)(B0);                            // 8 MB
  float* ws_gfull        = (float*)(B0 + 8388608);                  // 8 MB
  unsigned short* vT     = (unsigned short*)(B0);                   // 16 MB
  unsigned short* oT     = (unsigned short*)(B0);                   // 16 MB
  // region C
  char* C0 = w + 50331648;
  unsigned short* fhi    = (unsigned short*)(C0);                   // 4,194,304
  unsigned short* flo    = (unsigned short*)(C0 + 4194304);         // 4,194,304
  unsigned short* ghi    = (unsigned short*)(C0 + 8388608);         // 1,048,576
  unsigned short* glo    = (unsigned short*)(C0 + 9437184);         // 1,048,576
  unsigned short* whbf   = (unsigned short*)(C0 + 10485760);        //   262,144
  unsigned short* wvbf   = (unsigned short*)(C0 + 10747904);        //   262,144
  float* wft             = (float*)(C0 + 11010048);                 //   131,072
  float* wgt             = (float*)(C0 + 11141120);                 //   131,072  (end 61.6 MB)

  transpose_k<<<(64 * 512 + 255) / 256, 256, 0, stream>>>(Wf, wft, 64, 512);
  transpose_k<<<(64 * 512 + 255) / 256, 256, 0, stream>>>(Wg, wgt, 64, 512);
  cast_bf16_k<<<(131072 + 255) / 256, 256, 0, stream>>>(Wh, whbf, 131072);
  cast_bf16_k<<<(131072 + 255) / 256, 256, 0, stream>>>(Wv, wvbf, 131072);

  xT_k<<<dim3(64, 8, 8), 256, 0, stream>>>(x, xT);

  conv_tile<512><<<dim3(64, 1, 8), 256, 0, stream>>>(x, wft, bf, ws_f, 64);
  splitT_f_k<<<dim3(64, 8), 256, 0, stream>>>(ws_f, fhi, flo);

  conv_tile<512><<<dim3(64, 1, 8), 256, 0, stream>>>(x, wgt, bg, ws_gfull, 64);
  poolsplitT_g_k<<<dim3(32, 8), 256, 0, stream>>>(ws_gfull, ghi, glo);

  conv_mfma<512, 0><<<dim3(64, 4, 8), 256, 0, stream>>>(xT, whbf, bh, vT, 256, nullptr, nullptr);
  pool_v_k<<<8192, 256, 0, stream>>>(vT, v_pool);

  attn_mfma<<<dim3(256, 8), 256, 0, stream>>>(fhi, flo, ghi, glo, v_pool, oT);

  conv_mfma<256, 1><<<dim3(64, 8, 8), 256, 0, stream>>>(oT, wvbf, bv, out, 512, x, gamma);
}

// Round 3
// 400.662 us; speedup vs baseline: 2.7625x; 1.4341x over previous
//
#include <hip/hip_runtime.h>
#include <cstddef>

typedef __attribute__((ext_vector_type(4))) float f32x4;
typedef __attribute__((ext_vector_type(8))) short bf16x8;

#define MFMA16(A, B, C) __builtin_amdgcn_mfma_f32_16x16x32_bf16(A, B, C, 0, 0, 0)

__device__ __forceinline__ unsigned short f2bf(float f) {
  unsigned u = __float_as_uint(f);
  u += 0x7fffu + ((u >> 16) & 1u);
  return (unsigned short)(u >> 16);
}
__device__ __forceinline__ float bf2f(unsigned short s) {
  return __uint_as_float(((unsigned)s) << 16);
}

// ---------- weight prep ----------

__global__ void split_cast_k(const float* __restrict__ in, unsigned short* __restrict__ hi,
                             unsigned short* __restrict__ lo, int n) {
  int i = blockIdx.x * 256 + threadIdx.x;
  if (i < n) {
    float v = in[i];
    unsigned short h = f2bf(v);
    hi[i] = h;
    lo[i] = f2bf(v - bf2f(h));
  }
}

__global__ void cast_bf16_k(const float* __restrict__ in, unsigned short* __restrict__ out, int n) {
  int i = blockIdx.x * 256 + threadIdx.x;
  if (i < n) out[i] = f2bf(in[i]);
}

// ---------- f/g conv: split-MFMA from x (staged+split in LDS). 128n x 64oc tile ----------
// POOL=0: write ohi/olo [b][4096][64].  POOL=1: pool 2x2 -> ohi/olo [b][1024][64].

template<int POOL>
__global__ __launch_bounds__(256)
void conv_fg(const float* __restrict__ x, const unsigned short* __restrict__ wh_,
             const unsigned short* __restrict__ wl_, const float* __restrict__ bias,
             unsigned short* __restrict__ ohi, unsigned short* __restrict__ olo)
{
  __shared__ __align__(16) char smem[POOL ? 128 * 66 * 4 : 20480];
  unsigned short (*ah)[40] = (unsigned short(*)[40])smem;              // 10,240 B
  unsigned short (*al)[40] = (unsigned short(*)[40])(smem + 10240);    // 10,240 B
  float (*pl)[66] = (float(*)[66])smem;                                // POOL epilogue reuse

  const int b = blockIdx.y, n0 = blockIdx.x * 128;
  const int tid = threadIdx.x, w = tid >> 6, lane = tid & 63, q = lane & 15, qt = lane >> 4;

  f32x4 acc[2][4];
  #pragma unroll
  for (int nt = 0; nt < 2; ++nt)
    #pragma unroll
    for (int ot = 0; ot < 4; ++ot) acc[nt][ot] = (f32x4){0.f, 0.f, 0.f, 0.f};

  for (int c0 = 0; c0 < 512; c0 += 32) {
    #pragma unroll
    for (int i = 0; i < 16; ++i) {
      int idx = tid + i * 256;          // 32 k x 128 n
      int k = idx >> 7, nl = idx & 127;
      float v = x[((size_t)(b * 512 + c0 + k)) * 4096 + n0 + nl];
      unsigned short h = f2bf(v);
      ah[nl][k] = h;
      al[nl][k] = f2bf(v - bf2f(h));
    }
    __syncthreads();
    bf16x8 A_h[2], A_l[2], B_h[4], B_l[4];
    #pragma unroll
    for (int nt = 0; nt < 2; ++nt) {
      A_h[nt] = *(const bf16x8*)&ah[w * 32 + nt * 16 + q][qt * 8];
      A_l[nt] = *(const bf16x8*)&al[w * 32 + nt * 16 + q][qt * 8];
    }
    #pragma unroll
    for (int ot = 0; ot < 4; ++ot) {
      size_t wb = (size_t)(ot * 16 + q) * 512 + c0 + qt * 8;
      B_h[ot] = *(const bf16x8*)(wh_ + wb);
      B_l[ot] = *(const bf16x8*)(wl_ + wb);
    }
    #pragma unroll
    for (int nt = 0; nt < 2; ++nt)
      #pragma unroll
      for (int ot = 0; ot < 4; ++ot) {
        acc[nt][ot] = MFMA16(A_h[nt], B_h[ot], acc[nt][ot]);
        acc[nt][ot] = MFMA16(A_h[nt], B_l[ot], acc[nt][ot]);
        acc[nt][ot] = MFMA16(A_l[nt], B_h[ot], acc[nt][ot]);
      }
    __syncthreads();
  }

  if (POOL == 0) {
    #pragma unroll
    for (int nt = 0; nt < 2; ++nt)
      #pragma unroll
      for (int ot = 0; ot < 4; ++ot)
        #pragma unroll
        for (int r = 0; r < 4; ++r) {
          int n = n0 + w * 32 + nt * 16 + qt * 4 + r;
          int oc = ot * 16 + q;
          float v = acc[nt][ot][r] + bias[oc];
          unsigned short h = f2bf(v);
          size_t o = ((size_t)b * 4096 + n) * 64 + oc;
          ohi[o] = h;
          olo[o] = f2bf(v - bf2f(h));
        }
  } else {
    #pragma unroll
    for (int nt = 0; nt < 2; ++nt)
      #pragma unroll
      for (int ot = 0; ot < 4; ++ot)
        #pragma unroll
        for (int r = 0; r < 4; ++r)
          pl[w * 32 + nt * 16 + qt * 4 + r][ot * 16 + q] = acc[nt][ot][r];
    __syncthreads();
    const int hp = blockIdx.x;
    const int c = tid & 63;
    #pragma unroll
    for (int it = 0; it < 8; ++it) {
      int wp = (tid >> 6) + it * 4;
      float v = fmaxf(fmaxf(pl[2 * wp][c], pl[2 * wp + 1][c]),
                      fmaxf(pl[64 + 2 * wp][c], pl[65 + 2 * wp][c])) + bias[c];
      unsigned short h = f2bf(v);
      size_t o = ((size_t)b * 1024 + hp * 32 + wp) * 64 + c;
      ohi[o] = h;
      olo[o] = f2bf(v - bf2f(h));
    }
  }
}

// ---------- v conv: hi-only MFMA, 128n x 128oc tile, fused 2x2 pool -> vp[b][256][1024] ----------

__global__ __launch_bounds__(256)
void conv_v(const float* __restrict__ x, const unsigned short* __restrict__ wh_,
            const float* __restrict__ bias, unsigned short* __restrict__ vp)
{
  __shared__ __align__(16) char smem[128 * 65 * 4];
  unsigned short (*ah)[40] = (unsigned short(*)[40])smem;
  float (*pl)[65] = (float(*)[65])smem;

  const int b = blockIdx.z, oc0 = blockIdx.y * 128, hp = blockIdx.x, n0 = hp * 128;
  const int tid = threadIdx.x, w = tid >> 6, lane = tid & 63, q = lane & 15, qt = lane >> 4;

  f32x4 acc[2][8];
  #pragma unroll
  for (int nt = 0; nt < 2; ++nt)
    #pragma unroll
    for (int ot = 0; ot < 8; ++ot) acc[nt][ot] = (f32x4){0.f, 0.f, 0.f, 0.f};

  for (int c0 = 0; c0 < 512; c0 += 32) {
    #pragma unroll
    for (int i = 0; i < 16; ++i) {
      int idx = tid + i * 256;
      int k = idx >> 7, nl = idx & 127;
      ah[nl][k] = f2bf(x[((size_t)(b * 512 + c0 + k)) * 4096 + n0 + nl]);
    }
    __syncthreads();
    bf16x8 A_[2], B_[8];
    #pragma unroll
    for (int nt = 0; nt < 2; ++nt)
      A_[nt] = *(const bf16x8*)&ah[w * 32 + nt * 16 + q][qt * 8];
    #pragma unroll
    for (int ot = 0; ot < 8; ++ot)
      B_[ot] = *(const bf16x8*)(wh_ + (size_t)(oc0 + ot * 16 + q) * 512 + c0 + qt * 8);
    #pragma unroll
    for (int nt = 0; nt < 2; ++nt)
      #pragma unroll
      for (int ot = 0; ot < 8; ++ot)
        acc[nt][ot] = MFMA16(A_[nt], B_[ot], acc[nt][ot]);
    __syncthreads();
  }

  #pragma unroll
  for (int oh = 0; oh < 2; ++oh) {
    if (oh) __syncthreads();
    #pragma unroll
    for (int nt = 0; nt < 2; ++nt)
      #pragma unroll
      for (int ot4 = 0; ot4 < 4; ++ot4)
        #pragma unroll
        for (int r = 0; r < 4; ++r)
          pl[w * 32 + nt * 16 + qt * 4 + r][ot4 * 16 + q] = acc[nt][oh * 4 + ot4][r];
    __syncthreads();
    const int wp = tid & 31;
    #pragma unroll
    for (int it = 0; it < 8; ++it) {
      int cc = (tid >> 5) + it * 8;
      float v = fmaxf(fmaxf(pl[2 * wp][cc], pl[2 * wp + 1][cc]),
                      fmaxf(pl[64 + 2 * wp][cc], pl[65 + 2 * wp][cc])) + bias[oc0 + oh * 64 + cc];
      vp[((size_t)(b * 256) + oc0 + oh * 64 + cc) * 1024 + hp * 32 + wp] = f2bf(v);
    }
  }
}

// ---------- fused attention ----------

#define PROW 1032

__global__ __launch_bounds__(256, 4)
void attn_mfma(const unsigned short* __restrict__ fhi, const unsigned short* __restrict__ flo,
               const unsigned short* __restrict__ ghi, const unsigned short* __restrict__ glo,
               const unsigned short* __restrict__ vp, unsigned short* __restrict__ oT)
{
  __shared__ unsigned short P[16 * PROW];
  __shared__ float redm[4][16], reds[4][16];
  const int b = blockIdx.y, n0 = blockIdx.x * 16;
  const int tid = threadIdx.x, w = tid >> 6, lane = tid & 63, q = lane & 15, qt = lane >> 4;

  const size_t fb = ((size_t)b * 4096 + n0 + q) * 64 + qt * 8;
  bf16x8 fh0 = *(const bf16x8*)(fhi + fb);
  bf16x8 fh1 = *(const bf16x8*)(fhi + fb + 32);
  bf16x8 fl0 = *(const bf16x8*)(flo + fb);
  bf16x8 fl1 = *(const bf16x8*)(flo + fb + 32);

  f32x4 sa[16];
  #pragma unroll
  for (int t = 0; t < 16; ++t) sa[t] = (f32x4){0.f, 0.f, 0.f, 0.f};

  const size_t g0 = ((size_t)b * 1024 + w * 256 + q) * 64 + qt * 8;
  bf16x8 cah0 = *(const bf16x8*)(ghi + g0);
  bf16x8 cah1 = *(const bf16x8*)(ghi + g0 + 32);
  bf16x8 cal0 = *(const bf16x8*)(glo + g0);
  bf16x8 cal1 = *(const bf16x8*)(glo + g0 + 32);

  #pragma unroll
  for (int t = 0; t < 16; ++t) {
    bf16x8 nah0, nah1, nal0, nal1;
    if (t < 15) {
      size_t gb = g0 + (size_t)(t + 1) * 16 * 64;
      nah0 = *(const bf16x8*)(ghi + gb);
      nah1 = *(const bf16x8*)(ghi + gb + 32);
      nal0 = *(const bf16x8*)(glo + gb);
      nal1 = *(const bf16x8*)(glo + gb + 32);
    }
    sa[t] = MFMA16(cah0, fh0, sa[t]);
    sa[t] = MFMA16(cah1, fh1, sa[t]);
    sa[t] = MFMA16(cah0, fl0, sa[t]);
    sa[t] = MFMA16(cah1, fl1, sa[t]);
    sa[t] = MFMA16(cal0, fh0, sa[t]);
    sa[t] = MFMA16(cal1, fh1, sa[t]);
    if (t < 15) { cah0 = nah0; cah1 = nah1; cal0 = nal0; cal1 = nal1; }
  }

  float mx = -3.0e38f;
  #pragma unroll
  for (int t = 0; t < 16; ++t)
    mx = fmaxf(mx, fmaxf(fmaxf(sa[t][0], sa[t][1]), fmaxf(sa[t][2], sa[t][3])));
  mx = fmaxf(mx, __shfl_xor(mx, 16));
  mx = fmaxf(mx, __shfl_xor(mx, 32));
  if (lane < 16) redm[w][lane] = mx;
  __syncthreads();
  const float gmx = fmaxf(fmaxf(redm[0][q], redm[1][q]), fmaxf(redm[2][q], redm[3][q]));

  float sum = 0.f;
  #pragma unroll
  for (int t = 0; t < 16; ++t) {
    #pragma unroll
    for (int r = 0; r < 4; ++r) {
      float p = __expf(sa[t][r] - gmx);
      sa[t][r] = p;
      sum += p;
    }
  }
  sum += __shfl_xor(sum, 16);
  sum += __shfl_xor(sum, 32);
  if (lane < 16) reds[w][lane] = sum;

  #pragma unroll
  for (int t = 0; t < 16; ++t) {
    unsigned lo = (unsigned)f2bf(sa[t][0]) | ((unsigned)f2bf(sa[t][1]) << 16);
    unsigned hi = (unsigned)f2bf(sa[t][2]) | ((unsigned)f2bf(sa[t][3]) << 16);
    uint2 pk; pk.x = lo; pk.y = hi;
    *(uint2*)(&P[q * PROW + w * 256 + t * 16 + qt * 4]) = pk;
  }
  __syncthreads();
  const float rinv = 1.0f / (reds[0][q] + reds[1][q] + reds[2][q] + reds[3][q]);

  f32x4 oacc[4];
  #pragma unroll
  for (int c4 = 0; c4 < 4; ++c4) oacc[c4] = (f32x4){0.f, 0.f, 0.f, 0.f};

  const size_t v0 = ((size_t)b * 256 + w * 64 + q) * 1024 + qt * 8;
  bf16x8 cv0 = *(const bf16x8*)(vp + v0);
  bf16x8 cv1 = *(const bf16x8*)(vp + v0 + 16384);
  bf16x8 cv2 = *(const bf16x8*)(vp + v0 + 32768);
  bf16x8 cv3 = *(const bf16x8*)(vp + v0 + 49152);

  #pragma unroll
  for (int ks = 0; ks < 32; ++ks) {
    bf16x8 pb = *(const bf16x8*)(&P[q * PROW + ks * 32 + qt * 8]);
    bf16x8 nv0, nv1, nv2, nv3;
    if (ks < 31) {
      size_t vb = v0 + (size_t)(ks + 1) * 32;
      nv0 = *(const bf16x8*)(vp + vb);
      nv1 = *(const bf16x8*)(vp + vb + 16384);
      nv2 = *(const bf16x8*)(vp + vb + 32768);
      nv3 = *(const bf16x8*)(vp + vb + 49152);
    }
    oacc[0] = MFMA16(cv0, pb, oacc[0]);
    oacc[1] = MFMA16(cv1, pb, oacc[1]);
    oacc[2] = MFMA16(cv2, pb, oacc[2]);
    oacc[3] = MFMA16(cv3, pb, oacc[3]);
    if (ks < 31) { cv0 = nv0; cv1 = nv1; cv2 = nv2; cv3 = nv3; }
  }

  #pragma unroll
  for (int c4 = 0; c4 < 4; ++c4) {
    unsigned lo = (unsigned)f2bf(oacc[c4][0] * rinv) | ((unsigned)f2bf(oacc[c4][1] * rinv) << 16);
    unsigned hi = (unsigned)f2bf(oacc[c4][2] * rinv) | ((unsigned)f2bf(oacc[c4][3] * rinv) << 16);
    uint2 pk; pk.x = lo; pk.y = hi;
    *(uint2*)(oT + ((size_t)b * 4096 + n0 + q) * 256 + (w * 4 + c4) * 16 + qt * 4) = pk;
  }
}

// ---------- final conv: 128n x 128oc, out = gamma*(oT.Wv + bv) + x ----------

__global__ __launch_bounds__(256)
void conv_final(const unsigned short* __restrict__ A, const unsigned short* __restrict__ W,
                const float* __restrict__ bias, float* __restrict__ out,
                const float* __restrict__ resid, const float* __restrict__ gamma_p)
{
  __shared__ float lds[128][65];
  const int b = blockIdx.z, oc0 = blockIdx.y * 128, n0 = blockIdx.x * 128;
  const int tid = threadIdx.x, w = tid >> 6, lane = tid & 63, q = lane & 15, qt = lane >> 4;

  f32x4 acc[2][8];
  #pragma unroll
  for (int nt = 0; nt < 2; ++nt)
    #pragma unroll
    for (int ot = 0; ot < 8; ++ot) acc[nt][ot] = (f32x4){0.f, 0.f, 0.f, 0.f};

  const size_t a0 = ((size_t)b * 4096 + n0 + w * 32 + q) * 256 + qt * 8;
  #pragma unroll
  for (int ks = 0; ks < 8; ++ks) {
    bf16x8 A_[2], B_[8];
    #pragma unroll
    for (int nt = 0; nt < 2; ++nt)
      A_[nt] = *(const bf16x8*)(A + a0 + nt * 16 * 256 + ks * 32);
    #pragma unroll
    for (int ot = 0; ot < 8; ++ot)
      B_[ot] = *(const bf16x8*)(W + (size_t)(oc0 + ot * 16 + q) * 256 + ks * 32 + qt * 8);
    #pragma unroll
    for (int nt = 0; nt < 2; ++nt)
      #pragma unroll
      for (int ot = 0; ot < 8; ++ot)
        acc[nt][ot] = MFMA16(A_[nt], B_[ot], acc[nt][ot]);
  }

  const float gm = gamma_p[0];
  #pragma unroll
  for (int oh = 0; oh < 2; ++oh) {
    if (oh) __syncthreads();
    #pragma unroll
    for (int nt = 0; nt < 2; ++nt)
      #pragma unroll
      for (int ot4 = 0; ot4 < 4; ++ot4)
        #pragma unroll
        for (int r = 0; r < 4; ++r)
          lds[w * 32 + nt * 16 + qt * 4 + r][ot4 * 16 + q] = acc[nt][oh * 4 + ot4][r];
    __syncthreads();
    #pragma unroll
    for (int it = 0; it < 32; ++it) {
      int nl = tid & 127;
      int ocl = (tid >> 7) + it * 2;
      int oc = oc0 + oh * 64 + ocl;
      size_t o = ((size_t)(b * 512) + oc) * 4096 + n0 + nl;
      out[o] = gm * (lds[nl][ocl] + bias[oc]) + resid[o];
    }
  }
}

// ---------- launch ----------

extern "C" void kernel_launch(void* const* d_in, const int* in_sizes, int n_in,
                              void* d_out, int out_size, void* d_ws, size_t ws_size,
                              hipStream_t stream) {
  const float* x     = (const float*)d_in[0];
  const float* Wf    = (const float*)d_in[1];
  const float* bf    = (const float*)d_in[2];
  const float* Wg    = (const float*)d_in[3];
  const float* bg    = (const float*)d_in[4];
  const float* Wh    = (const float*)d_in[5];
  const float* bh    = (const float*)d_in[6];
  const float* Wv    = (const float*)d_in[7];
  const float* bv    = (const float*)d_in[8];
  const float* gamma = (const float*)d_in[9];
  float* out = (float*)d_out;
  char* w = (char*)d_ws;

  unsigned short* fhi = (unsigned short*)(w);                 // 4 MB  [8][4096][64]
  unsigned short* flo = (unsigned short*)(w + 4194304);       // 4 MB
  unsigned short* ghi = (unsigned short*)(w + 8388608);       // 1 MB  [8][1024][64]
  unsigned short* glo = (unsigned short*)(w + 9437184);       // 1 MB
  unsigned short* vp  = (unsigned short*)(w + 10485760);      // 4 MB  [8][256][1024]
  unsigned short* oT  = (unsigned short*)(w + 14680064);      // 16 MB [8][4096][256]
  unsigned short* wfh = (unsigned short*)(w + 31457280);      // 64 KB [64][512]
  unsigned short* wfl = (unsigned short*)(w + 31522816);
  unsigned short* wgh = (unsigned short*)(w + 31588352);
  unsigned short* wgl = (unsigned short*)(w + 31653888);
  unsigned short* whb = (unsigned short*)(w + 31719424);      // 256 KB [256][512]
  unsigned short* wvb = (unsigned short*)(w + 31981568);      // 256 KB [512][256]

  split_cast_k<<<128, 256, 0, stream>>>(Wf, wfh, wfl, 32768);
  split_cast_k<<<128, 256, 0, stream>>>(Wg, wgh, wgl, 32768);
  cast_bf16_k<<<512, 256, 0, stream>>>(Wh, whb, 131072);
  cast_bf16_k<<<512, 256, 0, stream>>>(Wv, wvb, 131072);

  conv_fg<0><<<dim3(32, 8), 256, 0, stream>>>(x, wfh, wfl, bf, fhi, flo);
  conv_fg<1><<<dim3(32, 8), 256, 0, stream>>>(x, wgh, wgl, bg, ghi, glo);
  conv_v<<<dim3(32, 2, 8), 256, 0, stream>>>(x, whb, bh, vp);

  attn_mfma<<<dim3(256, 8), 256, 0, stream>>>(fhi, flo, ghi, glo, vp, oT);

  conv_final<<<dim3(32, 4, 8), 256, 0, stream>>>(oT, wvb, bv, out, x, gamma);
}

// Round 4
// 258.153 us; speedup vs baseline: 4.2876x; 1.5520x over previous
//
#include <hip/hip_runtime.h>
#include <cstddef>

typedef __attribute__((ext_vector_type(4))) float f32x4;
typedef __attribute__((ext_vector_type(8))) short bf16x8;

#define MFMA16(A, B, C) __builtin_amdgcn_mfma_f32_16x16x32_bf16(A, B, C, 0, 0, 0)

__device__ __forceinline__ unsigned short f2bf(float f) {
  unsigned u = __float_as_uint(f);
  u += 0x7fffu + ((u >> 16) & 1u);
  return (unsigned short)(u >> 16);
}
__device__ __forceinline__ float bf2f(unsigned short s) {
  return __uint_as_float(((unsigned)s) << 16);
}

// ---------- weight prep ----------

__global__ void split_cast_k(const float* __restrict__ in, unsigned short* __restrict__ hi,
                             unsigned short* __restrict__ lo, int n) {
  int i = blockIdx.x * 256 + threadIdx.x;
  if (i < n) {
    float v = in[i];
    unsigned short h = f2bf(v);
    hi[i] = h;
    lo[i] = f2bf(v - bf2f(h));
  }
}

__global__ void cast_bf16_k(const float* __restrict__ in, unsigned short* __restrict__ out, int n) {
  int i = blockIdx.x * 256 + threadIdx.x;
  if (i < n) out[i] = f2bf(in[i]);
}

// ---------- fused f+g conv: split-MFMA from x staged in LDS. 128n tile ----------
// f: split write [b][4096][64].  g: 2x2 pool + split write [b][1024][64].

__global__ __launch_bounds__(256)
void conv_fg(const float* __restrict__ x,
             const unsigned short* __restrict__ wfh_, const unsigned short* __restrict__ wfl_,
             const unsigned short* __restrict__ wgh_, const unsigned short* __restrict__ wgl_,
             const float* __restrict__ bf_, const float* __restrict__ bg_,
             unsigned short* __restrict__ fhi, unsigned short* __restrict__ flo,
             unsigned short* __restrict__ ghi, unsigned short* __restrict__ glo)
{
  __shared__ __align__(16) char smem[33792];
  unsigned short (*ah)[40] = (unsigned short(*)[40])smem;
  unsigned short (*al)[40] = (unsigned short(*)[40])(smem + 10240);
  float (*pl)[66] = (float(*)[66])smem;

  const int b = blockIdx.y, hp = blockIdx.x, n0 = hp * 128;
  const int tid = threadIdx.x, w = tid >> 6, lane = tid & 63, q = lane & 15, qt = lane >> 4;

  f32x4 accf[2][4], accg[2][4];
  #pragma unroll
  for (int nt = 0; nt < 2; ++nt)
    #pragma unroll
    for (int ot = 0; ot < 4; ++ot) {
      accf[nt][ot] = (f32x4){0.f, 0.f, 0.f, 0.f};
      accg[nt][ot] = (f32x4){0.f, 0.f, 0.f, 0.f};
    }

  for (int c0 = 0; c0 < 512; c0 += 32) {
    #pragma unroll
    for (int i = 0; i < 16; ++i) {
      int idx = tid + i * 256;
      int k = idx >> 7, nl = idx & 127;
      float v = x[((size_t)(b * 512 + c0 + k)) * 4096 + n0 + nl];
      unsigned short h = f2bf(v);
      ah[nl][k] = h;
      al[nl][k] = f2bf(v - bf2f(h));
    }
    __syncthreads();
    bf16x8 Ah[2], Al[2];
    #pragma unroll
    for (int nt = 0; nt < 2; ++nt) {
      Ah[nt] = *(const bf16x8*)&ah[w * 32 + nt * 16 + q][qt * 8];
      Al[nt] = *(const bf16x8*)&al[w * 32 + nt * 16 + q][qt * 8];
    }
    {
      bf16x8 Bh[4], Bl[4];
      #pragma unroll
      for (int ot = 0; ot < 4; ++ot) {
        size_t wb = (size_t)(ot * 16 + q) * 512 + c0 + qt * 8;
        Bh[ot] = *(const bf16x8*)(wfh_ + wb);
        Bl[ot] = *(const bf16x8*)(wfl_ + wb);
      }
      #pragma unroll
      for (int nt = 0; nt < 2; ++nt)
        #pragma unroll
        for (int ot = 0; ot < 4; ++ot) {
          accf[nt][ot] = MFMA16(Ah[nt], Bh[ot], accf[nt][ot]);
          accf[nt][ot] = MFMA16(Ah[nt], Bl[ot], accf[nt][ot]);
          accf[nt][ot] = MFMA16(Al[nt], Bh[ot], accf[nt][ot]);
        }
    }
    {
      bf16x8 Bh[4], Bl[4];
      #pragma unroll
      for (int ot = 0; ot < 4; ++ot) {
        size_t wb = (size_t)(ot * 16 + q) * 512 + c0 + qt * 8;
        Bh[ot] = *(const bf16x8*)(wgh_ + wb);
        Bl[ot] = *(const bf16x8*)(wgl_ + wb);
      }
      #pragma unroll
      for (int nt = 0; nt < 2; ++nt)
        #pragma unroll
        for (int ot = 0; ot < 4; ++ot) {
          accg[nt][ot] = MFMA16(Ah[nt], Bh[ot], accg[nt][ot]);
          accg[nt][ot] = MFMA16(Ah[nt], Bl[ot], accg[nt][ot]);
          accg[nt][ot] = MFMA16(Al[nt], Bh[ot], accg[nt][ot]);
        }
    }
    __syncthreads();
  }

  // f epilogue: split write (registers only)
  #pragma unroll
  for (int nt = 0; nt < 2; ++nt)
    #pragma unroll
    for (int ot = 0; ot < 4; ++ot)
      #pragma unroll
      for (int r = 0; r < 4; ++r) {
        int n = n0 + w * 32 + nt * 16 + qt * 4 + r;
        int oc = ot * 16 + q;
        float v = accf[nt][ot][r] + bf_[oc];
        unsigned short h = f2bf(v);
        size_t o = ((size_t)b * 4096 + n) * 64 + oc;
        fhi[o] = h;
        flo[o] = f2bf(v - bf2f(h));
      }

  // g epilogue: pool via LDS
  #pragma unroll
  for (int nt = 0; nt < 2; ++nt)
    #pragma unroll
    for (int ot = 0; ot < 4; ++ot)
      #pragma unroll
      for (int r = 0; r < 4; ++r)
        pl[w * 32 + nt * 16 + qt * 4 + r][ot * 16 + q] = accg[nt][ot][r];
  __syncthreads();
  const int c = tid & 63;
  #pragma unroll
  for (int it = 0; it < 8; ++it) {
    int wp = (tid >> 6) + it * 4;
    float v = fmaxf(fmaxf(pl[2 * wp][c], pl[2 * wp + 1][c]),
                    fmaxf(pl[64 + 2 * wp][c], pl[65 + 2 * wp][c])) + bg_[c];
    unsigned short h = f2bf(v);
    size_t o = ((size_t)b * 1024 + hp * 32 + wp) * 64 + c;
    ghi[o] = h;
    glo[o] = f2bf(v - bf2f(h));
  }
}

// ---------- v conv: hi-only MFMA, 128n x 128oc tile, fused 2x2 pool -> vp[b][256][1024] ----------

__global__ __launch_bounds__(256)
void conv_v(const float* __restrict__ x, const unsigned short* __restrict__ wh_,
            const float* __restrict__ bias, unsigned short* __restrict__ vp)
{
  __shared__ __align__(16) char smem[128 * 65 * 4];
  unsigned short (*ah)[40] = (unsigned short(*)[40])smem;
  float (*pl)[65] = (float(*)[65])smem;

  const int b = blockIdx.z, oc0 = blockIdx.y * 128, hp = blockIdx.x, n0 = hp * 128;
  const int tid = threadIdx.x, w = tid >> 6, lane = tid & 63, q = lane & 15, qt = lane >> 4;

  f32x4 acc[2][8];
  #pragma unroll
  for (int nt = 0; nt < 2; ++nt)
    #pragma unroll
    for (int ot = 0; ot < 8; ++ot) acc[nt][ot] = (f32x4){0.f, 0.f, 0.f, 0.f};

  for (int c0 = 0; c0 < 512; c0 += 32) {
    #pragma unroll
    for (int i = 0; i < 16; ++i) {
      int idx = tid + i * 256;
      int k = idx >> 7, nl = idx & 127;
      ah[nl][k] = f2bf(x[((size_t)(b * 512 + c0 + k)) * 4096 + n0 + nl]);
    }
    __syncthreads();
    bf16x8 A_[2], B_[8];
    #pragma unroll
    for (int nt = 0; nt < 2; ++nt)
      A_[nt] = *(const bf16x8*)&ah[w * 32 + nt * 16 + q][qt * 8];
    #pragma unroll
    for (int ot = 0; ot < 8; ++ot)
      B_[ot] = *(const bf16x8*)(wh_ + (size_t)(oc0 + ot * 16 + q) * 512 + c0 + qt * 8);
    #pragma unroll
    for (int nt = 0; nt < 2; ++nt)
      #pragma unroll
      for (int ot = 0; ot < 8; ++ot)
        acc[nt][ot] = MFMA16(A_[nt], B_[ot], acc[nt][ot]);
    __syncthreads();
  }

  #pragma unroll
  for (int oh = 0; oh < 2; ++oh) {
    if (oh) __syncthreads();
    #pragma unroll
    for (int nt = 0; nt < 2; ++nt)
      #pragma unroll
      for (int ot4 = 0; ot4 < 4; ++ot4)
        #pragma unroll
        for (int r = 0; r < 4; ++r)
          pl[w * 32 + nt * 16 + qt * 4 + r][ot4 * 16 + q] = acc[nt][oh * 4 + ot4][r];
    __syncthreads();
    const int wp = tid & 31;
    #pragma unroll
    for (int it = 0; it < 8; ++it) {
      int cc = (tid >> 5) + it * 8;
      float v = fmaxf(fmaxf(pl[2 * wp][cc], pl[2 * wp + 1][cc]),
                      fmaxf(pl[64 + 2 * wp][cc], pl[65 + 2 * wp][cc])) + bias[oc0 + oh * 64 + cc];
      vp[((size_t)(b * 256) + oc0 + oh * 64 + cc) * 1024 + hp * 32 + wp] = f2bf(v);
    }
  }
}

// ---------- fused attention, QB=32 ----------

#define PROW 1040

__global__ __launch_bounds__(256, 2)
void attn_mfma(const unsigned short* __restrict__ fhi, const unsigned short* __restrict__ flo,
               const unsigned short* __restrict__ ghi, const unsigned short* __restrict__ glo,
               const unsigned short* __restrict__ vp, unsigned short* __restrict__ oT)
{
  __shared__ unsigned short P[32 * PROW];   // 66,560 B
  __shared__ float redm[4][2][16], reds[4][2][16];
  const int b = blockIdx.y, n0 = blockIdx.x * 32;
  const int tid = threadIdx.x, w = tid >> 6, lane = tid & 63, q = lane & 15, qt = lane >> 4;

  // f B-fragments for both q-subtiles (loop-invariant)
  bf16x8 fh00, fh01, fl00, fl01, fh10, fh11, fl10, fl11;
  {
    size_t fb0 = ((size_t)b * 4096 + n0 + q) * 64 + qt * 8;
    size_t fb1 = fb0 + 16 * 64;
    fh00 = *(const bf16x8*)(fhi + fb0); fh01 = *(const bf16x8*)(fhi + fb0 + 32);
    fl00 = *(const bf16x8*)(flo + fb0); fl01 = *(const bf16x8*)(flo + fb0 + 32);
    fh10 = *(const bf16x8*)(fhi + fb1); fh11 = *(const bf16x8*)(fhi + fb1 + 32);
    fl10 = *(const bf16x8*)(flo + fb1); fl11 = *(const bf16x8*)(flo + fb1 + 32);
  }

  f32x4 sa[16][2];
  #pragma unroll
  for (int t = 0; t < 16; ++t) {
    sa[t][0] = (f32x4){0.f, 0.f, 0.f, 0.f};
    sa[t][1] = (f32x4){0.f, 0.f, 0.f, 0.f};
  }

  const size_t g0 = ((size_t)b * 1024 + w * 256 + q) * 64 + qt * 8;
  bf16x8 gha0, gha1, gla0, gla1, ghb0, ghb1, glb0, glb1;

#define LOADGA(T) { size_t gb = g0 + (size_t)(T) * 1024; \
  gha0 = *(const bf16x8*)(ghi + gb); gha1 = *(const bf16x8*)(ghi + gb + 32); \
  gla0 = *(const bf16x8*)(glo + gb); gla1 = *(const bf16x8*)(glo + gb + 32); }
#define LOADGB(T) { size_t gb = g0 + (size_t)(T) * 1024; \
  ghb0 = *(const bf16x8*)(ghi + gb); ghb1 = *(const bf16x8*)(ghi + gb + 32); \
  glb0 = *(const bf16x8*)(glo + gb); glb1 = *(const bf16x8*)(glo + gb + 32); }
#define SMFMA(T, H0, H1, L0, L1) { \
  sa[T][0] = MFMA16(H0, fh00, sa[T][0]); sa[T][0] = MFMA16(H1, fh01, sa[T][0]); \
  sa[T][0] = MFMA16(H0, fl00, sa[T][0]); sa[T][0] = MFMA16(H1, fl01, sa[T][0]); \
  sa[T][0] = MFMA16(L0, fh00, sa[T][0]); sa[T][0] = MFMA16(L1, fh01, sa[T][0]); \
  sa[T][1] = MFMA16(H0, fh10, sa[T][1]); sa[T][1] = MFMA16(H1, fh11, sa[T][1]); \
  sa[T][1] = MFMA16(H0, fl10, sa[T][1]); sa[T][1] = MFMA16(H1, fl11, sa[T][1]); \
  sa[T][1] = MFMA16(L0, fh10, sa[T][1]); sa[T][1] = MFMA16(L1, fh11, sa[T][1]); }

  LOADGA(0)
  LOADGB(1)
  #pragma unroll
  for (int tp = 0; tp < 8; ++tp) {
    SMFMA(2 * tp, gha0, gha1, gla0, gla1)
    if (2 * tp + 2 < 16) LOADGA(2 * tp + 2)
    SMFMA(2 * tp + 1, ghb0, ghb1, glb0, glb1)
    if (2 * tp + 3 < 16) LOADGB(2 * tp + 3)
  }

  // softmax over m (rows live in-lane + across qt + across waves)
  float mx0 = -3.0e38f, mx1 = -3.0e38f;
  #pragma unroll
  for (int t = 0; t < 16; ++t) {
    mx0 = fmaxf(mx0, fmaxf(fmaxf(sa[t][0][0], sa[t][0][1]), fmaxf(sa[t][0][2], sa[t][0][3])));
    mx1 = fmaxf(mx1, fmaxf(fmaxf(sa[t][1][0], sa[t][1][1]), fmaxf(sa[t][1][2], sa[t][1][3])));
  }
  mx0 = fmaxf(mx0, __shfl_xor(mx0, 16)); mx0 = fmaxf(mx0, __shfl_xor(mx0, 32));
  mx1 = fmaxf(mx1, __shfl_xor(mx1, 16)); mx1 = fmaxf(mx1, __shfl_xor(mx1, 32));
  if (lane < 16) { redm[w][0][lane] = mx0; redm[w][1][lane] = mx1; }
  __syncthreads();
  const float gmx0 = fmaxf(fmaxf(redm[0][0][q], redm[1][0][q]), fmaxf(redm[2][0][q], redm[3][0][q]));
  const float gmx1 = fmaxf(fmaxf(redm[0][1][q], redm[1][1][q]), fmaxf(redm[2][1][q], redm[3][1][q]));

  float sum0 = 0.f, sum1 = 0.f;
  #pragma unroll
  for (int t = 0; t < 16; ++t) {
    #pragma unroll
    for (int r = 0; r < 4; ++r) {
      float p0 = __expf(sa[t][0][r] - gmx0);
      float p1 = __expf(sa[t][1][r] - gmx1);
      sa[t][0][r] = p0; sum0 += p0;
      sa[t][1][r] = p1; sum1 += p1;
    }
  }
  sum0 += __shfl_xor(sum0, 16); sum0 += __shfl_xor(sum0, 32);
  sum1 += __shfl_xor(sum1, 16); sum1 += __shfl_xor(sum1, 32);
  if (lane < 16) { reds[w][0][lane] = sum0; reds[w][1][lane] = sum1; }

  #pragma unroll
  for (int t = 0; t < 16; ++t) {
    uint2 pk0, pk1;
    pk0.x = (unsigned)f2bf(sa[t][0][0]) | ((unsigned)f2bf(sa[t][0][1]) << 16);
    pk0.y = (unsigned)f2bf(sa[t][0][2]) | ((unsigned)f2bf(sa[t][0][3]) << 16);
    pk1.x = (unsigned)f2bf(sa[t][1][0]) | ((unsigned)f2bf(sa[t][1][1]) << 16);
    pk1.y = (unsigned)f2bf(sa[t][1][2]) | ((unsigned)f2bf(sa[t][1][3]) << 16);
    *(uint2*)(&P[q * PROW + w * 256 + t * 16 + qt * 4]) = pk0;
    *(uint2*)(&P[(16 + q) * PROW + w * 256 + t * 16 + qt * 4]) = pk1;
  }
  __syncthreads();
  const float rinv0 = 1.0f / (reds[0][0][q] + reds[1][0][q] + reds[2][0][q] + reds[3][0][q]);
  const float rinv1 = 1.0f / (reds[0][1][q] + reds[1][1][q] + reds[2][1][q] + reds[3][1][q]);

  // PV: wave owns 64 cv rows, full m; 2-deep prefetched v fragments
  f32x4 oacc[4][2];
  #pragma unroll
  for (int c4 = 0; c4 < 4; ++c4) {
    oacc[c4][0] = (f32x4){0.f, 0.f, 0.f, 0.f};
    oacc[c4][1] = (f32x4){0.f, 0.f, 0.f, 0.f};
  }
  const size_t v0 = ((size_t)b * 256 + w * 64 + q) * 1024 + qt * 8;
  bf16x8 va0, va1, va2, va3, vb0, vb1, vb2, vb3;

#define LOADVA(KS) { size_t vb_ = v0 + (size_t)(KS) * 32; \
  va0 = *(const bf16x8*)(vp + vb_);         va1 = *(const bf16x8*)(vp + vb_ + 16384); \
  va2 = *(const bf16x8*)(vp + vb_ + 32768); va3 = *(const bf16x8*)(vp + vb_ + 49152); }
#define LOADVB(KS) { size_t vb_ = v0 + (size_t)(KS) * 32; \
  vb0 = *(const bf16x8*)(vp + vb_);         vb1 = *(const bf16x8*)(vp + vb_ + 16384); \
  vb2 = *(const bf16x8*)(vp + vb_ + 32768); vb3 = *(const bf16x8*)(vp + vb_ + 49152); }
#define PVMFMA(KS, V0, V1, V2, V3) { \
  bf16x8 pb0 = *(const bf16x8*)(&P[q * PROW + (KS) * 32 + qt * 8]); \
  bf16x8 pb1 = *(const bf16x8*)(&P[(16 + q) * PROW + (KS) * 32 + qt * 8]); \
  oacc[0][0] = MFMA16(V0, pb0, oacc[0][0]); oacc[1][0] = MFMA16(V1, pb0, oacc[1][0]); \
  oacc[2][0] = MFMA16(V2, pb0, oacc[2][0]); oacc[3][0] = MFMA16(V3, pb0, oacc[3][0]); \
  oacc[0][1] = MFMA16(V0, pb1, oacc[0][1]); oacc[1][1] = MFMA16(V1, pb1, oacc[1][1]); \
  oacc[2][1] = MFMA16(V2, pb1, oacc[2][1]); oacc[3][1] = MFMA16(V3, pb1, oacc[3][1]); }

  LOADVA(0)
  LOADVB(1)
  #pragma unroll
  for (int kp = 0; kp < 16; ++kp) {
    PVMFMA(2 * kp, va0, va1, va2, va3)
    if (2 * kp + 2 < 32) LOADVA(2 * kp + 2)
    PVMFMA(2 * kp + 1, vb0, vb1, vb2, vb3)
    if (2 * kp + 3 < 32) LOADVB(2 * kp + 3)
  }

  #pragma unroll
  for (int c4 = 0; c4 < 4; ++c4) {
    uint2 pk0, pk1;
    pk0.x = (unsigned)f2bf(oacc[c4][0][0] * rinv0) | ((unsigned)f2bf(oacc[c4][0][1] * rinv0) << 16);
    pk0.y = (unsigned)f2bf(oacc[c4][0][2] * rinv0) | ((unsigned)f2bf(oacc[c4][0][3] * rinv0) << 16);
    pk1.x = (unsigned)f2bf(oacc[c4][1][0] * rinv1) | ((unsigned)f2bf(oacc[c4][1][1] * rinv1) << 16);
    pk1.y = (unsigned)f2bf(oacc[c4][1][2] * rinv1) | ((unsigned)f2bf(oacc[c4][1][3] * rinv1) << 16);
    *(uint2*)(oT + ((size_t)b * 4096 + n0 + q) * 256 + w * 64 + c4 * 16 + qt * 4) = pk0;
    *(uint2*)(oT + ((size_t)b * 4096 + n0 + 16 + q) * 256 + w * 64 + c4 * 16 + qt * 4) = pk1;
  }
}

// ---------- final conv: 128n x 128oc, direct-fragment store, out = gamma*(oT.Wv + bv) + x ----------

__global__ __launch_bounds__(256)
void conv_final(const unsigned short* __restrict__ A, const unsigned short* __restrict__ W,
                const float* __restrict__ bias, float* __restrict__ out,
                const float* __restrict__ resid, const float* __restrict__ gamma_p)
{
  const int b = blockIdx.z, oc0 = blockIdx.y * 128, n0 = blockIdx.x * 128;
  const int tid = threadIdx.x, w = tid >> 6, lane = tid & 63, q = lane & 15, qt = lane >> 4;

  f32x4 acc[2][8];
  #pragma unroll
  for (int nt = 0; nt < 2; ++nt)
    #pragma unroll
    for (int ot = 0; ot < 8; ++ot) acc[nt][ot] = (f32x4){0.f, 0.f, 0.f, 0.f};

  const size_t a0 = ((size_t)b * 4096 + n0 + w * 32 + q) * 256 + qt * 8;
  #pragma unroll
  for (int ks = 0; ks < 8; ++ks) {
    bf16x8 A_[2], B_[8];
    #pragma unroll
    for (int nt = 0; nt < 2; ++nt)
      A_[nt] = *(const bf16x8*)(A + a0 + nt * 16 * 256 + ks * 32);
    #pragma unroll
    for (int ot = 0; ot < 8; ++ot)
      B_[ot] = *(const bf16x8*)(W + (size_t)(oc0 + ot * 16 + q) * 256 + ks * 32 + qt * 8);
    #pragma unroll
    for (int nt = 0; nt < 2; ++nt)
      #pragma unroll
      for (int ot = 0; ot < 8; ++ot)
        acc[nt][ot] = MFMA16(A_[nt], B_[ot], acc[nt][ot]);
  }

  const float gm = gamma_p[0];
  #pragma unroll
  for (int ot = 0; ot < 8; ++ot) {
    int oc = oc0 + ot * 16 + q;
    float bs = bias[oc];
    #pragma unroll
    for (int nt = 0; nt < 2; ++nt) {
      int n = n0 + w * 32 + nt * 16 + qt * 4;
      size_t o = ((size_t)(b * 512) + oc) * 4096 + n;
      float4 rs = *(const float4*)&resid[o];
      float4 ov;
      ov.x = gm * (acc[nt][ot][0] + bs) + rs.x;
      ov.y = gm * (acc[nt][ot][1] + bs) + rs.y;
      ov.z = gm * (acc[nt][ot][2] + bs) + rs.z;
      ov.w = gm * (acc[nt][ot][3] + bs) + rs.w;
      *(float4*)&out[o] = ov;
    }
  }
}

// ---------- launch ----------

extern "C" void kernel_launch(void* const* d_in, const int* in_sizes, int n_in,
                              void* d_out, int out_size, void* d_ws, size_t ws_size,
                              hipStream_t stream) {
  const float* x     = (const float*)d_in[0];
  const float* Wf    = (const float*)d_in[1];
  const float* bf    = (const float*)d_in[2];
  const float* Wg    = (const float*)d_in[3];
  const float* bg    = (const float*)d_in[4];
  const float* Wh    = (const float*)d_in[5];
  const float* bh    = (const float*)d_in[6];
  const float* Wv    = (const float*)d_in[7];
  const float* bv    = (const float*)d_in[8];
  const float* gamma = (const float*)d_in[9];
  float* out = (float*)d_out;
  char* w = (char*)d_ws;

  unsigned short* fhi = (unsigned short*)(w);                 // 4 MB  [8][4096][64]
  unsigned short* flo = (unsigned short*)(w + 4194304);       // 4 MB
  unsigned short* ghi = (unsigned short*)(w + 8388608);       // 1 MB  [8][1024][64]
  unsigned short* glo = (unsigned short*)(w + 9437184);       // 1 MB
  unsigned short* vp  = (unsigned short*)(w + 10485760);      // 4 MB  [8][256][1024]
  unsigned short* oT  = (unsigned short*)(w + 14680064);      // 16 MB [8][4096][256]
  unsigned short* wfh = (unsigned short*)(w + 31457280);      // 64 KB [64][512]
  unsigned short* wfl = (unsigned short*)(w + 31522816);
  unsigned short* wgh = (unsigned short*)(w + 31588352);
  unsigned short* wgl = (unsigned short*)(w + 31653888);
  unsigned short* whb = (unsigned short*)(w + 31719424);      // 256 KB [256][512]
  unsigned short* wvb = (unsigned short*)(w + 31981568);      // 256 KB [512][256]

  split_cast_k<<<128, 256, 0, stream>>>(Wf, wfh, wfl, 32768);
  split_cast_k<<<128, 256, 0, stream>>>(Wg, wgh, wgl, 32768);
  cast_bf16_k<<<512, 256, 0, stream>>>(Wh, whb, 131072);
  cast_bf16_k<<<512, 256, 0, stream>>>(Wv, wvb, 131072);

  conv_fg<<<dim3(32, 8), 256, 0, stream>>>(x, wfh, wfl, wgh, wgl, bf, bg, fhi, flo, ghi, glo);
  conv_v<<<dim3(32, 2, 8), 256, 0, stream>>>(x, whb, bh, vp);

  attn_mfma<<<dim3(128, 8), 256, 0, stream>>>(fhi, flo, ghi, glo, vp, oT);

  conv_final<<<dim3(32, 4, 8), 256, 0, stream>>>(oT, wvb, bv, out, x, gamma);
}